// Round 15
// baseline (992.907 us; speedup 1.0000x reference)
//
#include <hip/hip_runtime.h>
#include <hip/hip_bf16.h>
#include <math.h>

// Problem constants
#define B_    32
#define FIN   16
#define LIN   8192
#define LAT   64
#define L1V   8190      // length after k=3 valid conv
#define PN    200
#define PLEN  16
#define LOV   8175      // L1V - 16 + 1
#define NCLS  10
#define EPSV  1e-4f
#define MD0   320       // f32 offset of min_distances in d_out
#define CHK   256       // positions per block (R7-proven)
#define WIN   272       // window slots (CHK + 16)
#define FST   68        // fwin row stride in u16 (136 B: 2-way bank aliasing = free)
#define NPT   7         // proto tiles of 32 (200 padded to 224)
#define NFRAG (NPT * 16 * 4 * 64)   // 28672 pre-packed proto B-fragments
#define XSLOT 8256      // padded x slots per batch (zero tail; max read = 8225)
#define NTRB  (33 * B_) // transpose blocks: 33 tiles of 256 slots x 32 batches
#define TILEU ((size_t)16 * 4 * 64 * 8)   // u16 elems per proto tile in pk

typedef unsigned short u16;
typedef unsigned int   u32;
typedef short s16x8 __attribute__((ext_vector_type(8)));   // 8 bf16 (4 VGPRs)
typedef float f32x16 __attribute__((ext_vector_type(16))); // 32x32 MFMA accumulator

union FragU { uint2 u2[2]; s16x8 v; };

__device__ __forceinline__ u16 vf2b(float f) {
    union { float f; u32 u; } v; v.f = f;
    u32 u = v.u;
    return (u16)((u + 0x7fffu + ((u >> 16) & 1u)) >> 16);   // RNE
}

// K0 (fused prep): identical to R12/R14 (best measured).
__global__ void k_prep(const float* __restrict__ x, const float* __restrict__ we,
                       const float* __restrict__ wa, const float* __restrict__ pt,
                       u32* __restrict__ wsm, float* __restrict__ p2g,
                       u16* __restrict__ pk, u16* __restrict__ wpk,
                       u16* __restrict__ xT) {
    __shared__ u16 ls[16][256];          // 8 KB (transpose blocks only)
    const int t = threadIdx.x;

    if (blockIdx.x < NTRB) {
        // ---- coalesced transpose tile: batch b, slots [base, base+256) ----
        const int tile = blockIdx.x % 33;
        const int b    = blockIdx.x / 33;
        const int base = tile * 256;
        const float* xb = x + (size_t)b * FIN * LIN;
        const int slot = base + t;
        #pragma unroll
        for (int ch = 0; ch < 16; ++ch) {
            float v = (slot < LIN) ? xb[(size_t)ch * LIN + slot] : 0.f;
            ls[ch][t] = vf2b(v);
        }
        __syncthreads();
        if (slot < XSLOT) {
            u32 w[8];
            #pragma unroll
            for (int cp = 0; cp < 8; ++cp)
                w[cp] = ((u32)ls[2 * cp + 1][t] << 16) | (u32)ls[2 * cp][t];
            uint4* dst = (uint4*)(xT + ((size_t)b * XSLOT + slot) * 16);
            dst[0] = make_uint4(w[0], w[1], w[2], w[3]);
            dst[1] = make_uint4(w[4], w[5], w[6], w[7]);
        }
        return;
    }

    // ---- misc packing (grid-strided over 64 blocks x 256 threads) ----
    const int tid = (blockIdx.x - NTRB) * 256 + t;
    const int N   = 64 * 256;

    for (int j = tid; j < B_ * PN; j += N) wsm[j] = 0x7f7fffffu;

    // p2g wave-parallel: one wave per proto, lane sums 16 f32, butterfly reduce
    {
        const int wid = tid >> 6, nl = tid & 63, NW = N >> 6;
        for (int p = wid; p < 224; p += NW) {
            float s = 0.f;
            if (p < PN) {
                const float4* pr = (const float4*)(pt + (size_t)p * (LAT * PLEN)) + nl * 4;
                #pragma unroll
                for (int j = 0; j < 4; ++j) {
                    float4 v = pr[j];
                    s += v.x * v.x + v.y * v.y + v.z * v.z + v.w * v.w;
                }
            }
            #pragma unroll
            for (int off = 32; off; off >>= 1) s += __shfl_xor(s, off);
            if (nl == 0) p2g[p] = s;
        }
    }

    // pk: protos as per-lane MFMA B-frags (col=lane&31 proto, k=(lane>>5)*8+j ch, per tap/cs)
    for (int f = tid; f < NFRAG; f += N) {
        const int lane = f & 63;
        const int cs   = (f >> 6) & 3;
        const int tap  = (f >> 8) & 15;
        const int p7   = f >> 12;
        const int gp   = p7 * 32 + (lane & 31);
        const int chb  = cs * 16 + (lane >> 5) * 8;
        s16x8 v;
        if (gp < PN) {
            const float* src = pt + (size_t)gp * (LAT * PLEN) + (size_t)chb * PLEN + tap;
            #pragma unroll
            for (int j = 0; j < 8; ++j) v[j] = (short)vf2b(src[j * PLEN]);
        } else {
            #pragma unroll
            for (int j = 0; j < 8; ++j) v[j] = 0;
        }
        *(s16x8*)(pk + (size_t)f * 8) = v;
    }

    // wpk: 14 encoder B-frag groups x 64 lanes
    // grp 0..5 = we[tap 0..2][ntile 0..1] (K=16 ci); grp 6..13 = wa[cs 0..3][ntile 0..1]
    for (int f = tid; f < 14 * 64; f += N) {
        const int lane = f & 63, grp = f >> 6;
        const int col = lane & 31, kb = (lane >> 5) * 8;
        s16x8 v;
        if (grp < 6) {
            const int tau = grp >> 1, nt = grp & 1;
            #pragma unroll
            for (int j = 0; j < 8; ++j)
                v[j] = (short)vf2b(we[(size_t)(nt * 32 + col) * 48 + (kb + j) * 3 + tau]);
        } else {
            const int g2 = grp - 6, cs = g2 >> 1, nt = g2 & 1;
            #pragma unroll
            for (int j = 0; j < 8; ++j)
                v[j] = (short)vf2b(wa[(size_t)(nt * 32 + col) * 64 + cs * 16 + kb + j]);
        }
        *(s16x8*)(wpk + (size_t)f * 8) = v;
    }
}

// One tap's compute: 4 cs slices, A from LDS, B from the given register set.
#define TAP_COMPUTE(TAP, B0, B1, B2, B3)                                            \
    {                                                                               \
        const u16* apb = &fwin[(wv * 64 + m + (TAP)) * FST + koff];                 \
        FragU a0, a1;                                                               \
        a0.u2[0] = *(const uint2*)(apb);        a0.u2[1] = *(const uint2*)(apb + 4);\
        a1.u2[0] = *(const uint2*)(apb + 32*FST); a1.u2[1] = *(const uint2*)(apb + 32*FST + 4);\
        acc0 = __builtin_amdgcn_mfma_f32_32x32x16_bf16(a0.v, B0.v, acc0, 0, 0, 0);  \
        acc1 = __builtin_amdgcn_mfma_f32_32x32x16_bf16(a1.v, B0.v, acc1, 0, 0, 0);  \
        a0.u2[0] = *(const uint2*)(apb + 16);   a0.u2[1] = *(const uint2*)(apb + 20);\
        a1.u2[0] = *(const uint2*)(apb + 32*FST + 16); a1.u2[1] = *(const uint2*)(apb + 32*FST + 20);\
        acc0 = __builtin_amdgcn_mfma_f32_32x32x16_bf16(a0.v, B1.v, acc0, 0, 0, 0);  \
        acc1 = __builtin_amdgcn_mfma_f32_32x32x16_bf16(a1.v, B1.v, acc1, 0, 0, 0);  \
        a0.u2[0] = *(const uint2*)(apb + 32);   a0.u2[1] = *(const uint2*)(apb + 36);\
        a1.u2[0] = *(const uint2*)(apb + 32*FST + 32); a1.u2[1] = *(const uint2*)(apb + 32*FST + 36);\
        acc0 = __builtin_amdgcn_mfma_f32_32x32x16_bf16(a0.v, B2.v, acc0, 0, 0, 0);  \
        acc1 = __builtin_amdgcn_mfma_f32_32x32x16_bf16(a1.v, B2.v, acc1, 0, 0, 0);  \
        a0.u2[0] = *(const uint2*)(apb + 48);   a0.u2[1] = *(const uint2*)(apb + 52);\
        a1.u2[0] = *(const uint2*)(apb + 32*FST + 48); a1.u2[1] = *(const uint2*)(apb + 32*FST + 52);\
        acc0 = __builtin_amdgcn_mfma_f32_32x32x16_bf16(a0.v, B3.v, acc0, 0, 0, 0);  \
        acc1 = __builtin_amdgcn_mfma_f32_32x32x16_bf16(a1.v, B3.v, acc1, 0, 0, 0);  \
    }

// Load the 8 B-frags of tap-pair PJ (taps 2PJ, 2PJ+1) from tile base TB.
#define PAIR_LOAD(S0,S1,S2,S3,S4,S5,S6,S7, TB, PJ)                                  \
    S0.v = *(const s16x8*)((TB) + (size_t)((PJ) * 8 + 0) * 512);                    \
    S1.v = *(const s16x8*)((TB) + (size_t)((PJ) * 8 + 1) * 512);                    \
    S2.v = *(const s16x8*)((TB) + (size_t)((PJ) * 8 + 2) * 512);                    \
    S3.v = *(const s16x8*)((TB) + (size_t)((PJ) * 8 + 3) * 512);                    \
    S4.v = *(const s16x8*)((TB) + (size_t)((PJ) * 8 + 4) * 512);                    \
    S5.v = *(const s16x8*)((TB) + (size_t)((PJ) * 8 + 5) * 512);                    \
    S6.v = *(const s16x8*)((TB) + (size_t)((PJ) * 8 + 6) * 512);                    \
    S7.v = *(const s16x8*)((TB) + (size_t)((PJ) * 8 + 7) * 512);

// K1: block = (chunk of 256 positions, batch); grid 32x32, 4 blocks/CU fully resident.
// Phases 1-2 identical to R7/R12. Phase 3: pair-wise depth-2 register rotation —
// each 8-load group covered by a full 16-MFMA pair-compute (~250cy >= L2 latency);
// pass p7+1's first pair prefetched during pass p7's epilogue (no cold start).
// All fragment names static (rule #20). R14's depth-1 gave +6%; this doubles cover.
__global__ void __launch_bounds__(256, 4) k_dist(const u16* __restrict__ xT,
                                                 const u16* __restrict__ wpk,
                                                 const u16* __restrict__ pk,
                                                 u32* __restrict__ wsm,
                                                 const float* __restrict__ p2g) {
    __shared__ __align__(16) u16 fwin[WIN * FST];    // 36992 B, [slot][ch] bf16
    __shared__ float gwin[WIN];                      // 1088 B; g then s (-> 4 blk/CU)

    const int t  = threadIdx.x;
    const int ck = blockIdx.x;           // 0..31
    const int b  = blockIdx.y;           // 0..31
    const int base = ck * CHK;

    const int lane = t & 63;
    const int wv   = t >> 6;
    const int m    = lane & 31;
    const int half = lane >> 5;
    const int koff = half * 8;

    const u16* wpkl = wpk + (size_t)lane * 8;
    const u16* xTb  = xT + (size_t)b * XSLOT * 16;

    // ---------------- Phase 1: MFMA encoder ----------------
    #pragma unroll 1
    for (int mt = wv; mt < 9; mt += 4) {
        const int ar = mt * 32 + m;                  // this lane's A row
        // GEMM1: f1 = relu(conv3(x)), tap-decomposed, K=16 ci per tap
        f32x16 c1[2];
        #pragma unroll
        for (int i = 0; i < 16; ++i) { c1[0][i] = 0.f; c1[1][i] = 0.f; }
        #pragma unroll
        for (int tau = 0; tau < 3; ++tau) {
            FragU aF;
            aF.v = *(const s16x8*)(xTb + (size_t)(base + ar + tau) * 16 + koff);
            #pragma unroll
            for (int nt = 0; nt < 2; ++nt) {
                FragU bW; bW.v = *(const s16x8*)(wpkl + (size_t)(tau * 2 + nt) * 512);
                c1[nt] = __builtin_amdgcn_mfma_f32_32x32x16_bf16(aF.v, bW.v, c1[nt], 0, 0, 0);
            }
        }
        // write f1 (relu, bf16) into fwin rows of this tile (mask rows >= WIN for tile 8)
        #pragma unroll
        for (int nt = 0; nt < 2; ++nt) {
            const int col = nt * 32 + m;
            #pragma unroll
            for (int reg = 0; reg < 16; ++reg) {
                const int row = mt * 32 + (reg & 3) + 8 * (reg >> 2) + 4 * half;
                if (row < WIN) fwin[row * FST + col] = vf2b(fmaxf(c1[nt][reg], 0.f));
            }
        }
        // GEMM2: f2 = relu(wa . f1), K=64 in 4 cs slices; reads then overwrites same rows
        f32x16 c2[2];
        #pragma unroll
        for (int i = 0; i < 16; ++i) { c2[0][i] = 0.f; c2[1][i] = 0.f; }
        FragU a2[4];
        const int arc = (ar < WIN) ? ar : (WIN - 1);     // clamp tile-8 dead rows (stay in tile)
        #pragma unroll
        for (int cs = 0; cs < 4; ++cs) {
            const u16* ap = &fwin[arc * FST + cs * 16 + koff];
            a2[cs].u2[0] = *(const uint2*)ap;
            a2[cs].u2[1] = *(const uint2*)(ap + 4);
        }
        #pragma unroll
        for (int cs = 0; cs < 4; ++cs)
            #pragma unroll
            for (int nt = 0; nt < 2; ++nt) {
                FragU bW; bW.v = *(const s16x8*)(wpkl + (size_t)(6 + cs * 2 + nt) * 512);
                c2[nt] = __builtin_amdgcn_mfma_f32_32x32x16_bf16(a2[cs].v, bW.v, c2[nt], 0, 0, 0);
            }
        #pragma unroll
        for (int nt = 0; nt < 2; ++nt) {
            const int col = nt * 32 + m;
            #pragma unroll
            for (int reg = 0; reg < 16; ++reg) {
                const int row = mt * 32 + (reg & 3) + 8 * (reg >> 2) + 4 * half;
                if (row < WIN) fwin[row * FST + col] = vf2b(fmaxf(c2[nt][reg], 0.f));
            }
        }
    }
    __syncthreads();

    // ---------------- Phase 2a: per-slot g = ||f2||^2 ----------------
    {
        float g0 = 0.f, g1 = 0.f;
        const uint2* r0 = (const uint2*)(fwin + (size_t)t * FST);
        #pragma unroll
        for (int i = 0; i < 16; ++i) {
            uint2 v = r0[i];
            float a = __uint_as_float(v.x << 16);
            float bb = __uint_as_float(v.x & 0xffff0000u);
            float c = __uint_as_float(v.y << 16);
            float d = __uint_as_float(v.y & 0xffff0000u);
            g0 += a * a + bb * bb + c * c + d * d;
        }
        if (t < 16) {
            const uint2* r1 = (const uint2*)(fwin + (size_t)(CHK + t) * FST);
            #pragma unroll
            for (int i = 0; i < 16; ++i) {
                uint2 v = r1[i];
                float a = __uint_as_float(v.x << 16);
                float bb = __uint_as_float(v.x & 0xffff0000u);
                float c = __uint_as_float(v.y << 16);
                float d = __uint_as_float(v.y & 0xffff0000u);
                g1 += a * a + bb * bb + c * c + d * d;
            }
        }
        gwin[t] = g0;
        if (t < 16) gwin[CHK + t] = g1;
    }
    __syncthreads();

    // ---------------- Phase 2b: sliding patch-norm (poison tail), overwrite gwin ----
    {
        float sv = 0.f;
        #pragma unroll
        for (int k = 0; k < PLEN; ++k) sv += gwin[t + k];
        sv = (base + t < LOV) ? sv : 3.0e38f;
        __syncthreads();
        gwin[t] = sv;
    }
    __syncthreads();

    // ---------------- Phase 3: distance GEMM, pair-wise depth-2 B rotation ----------------
    const u16* pkl = pk + (size_t)lane * 8;
    FragU P0, P1, P2, P3, P4, P5, P6, P7;
    FragU Q0, Q1, Q2, Q3, Q4, Q5, Q6, Q7;
    PAIR_LOAD(P0, P1, P2, P3, P4, P5, P6, P7, pkl, 0);   // tile 0, pair 0

    #pragma unroll 1
    for (int p7 = 0; p7 < NPT; ++p7) {
        const u16* tb = pkl + (size_t)p7 * TILEU;
        f32x16 acc0, acc1;
        #pragma unroll
        for (int i = 0; i < 16; ++i) { acc0[i] = 0.f; acc1[i] = 0.f; }

        #pragma unroll
        for (int ip = 0; ip < 4; ++ip) {
            // Q <- pair 2ip+1 while computing pair 2ip from P
            PAIR_LOAD(Q0, Q1, Q2, Q3, Q4, Q5, Q6, Q7, tb, 2 * ip + 1);
            TAP_COMPUTE(4 * ip,     P0, P1, P2, P3);
            TAP_COMPUTE(4 * ip + 1, P4, P5, P6, P7);
            // P <- pair 2ip+2 (or next tile's pair 0 at ip=3) while computing Q's pair
            {
                const u16* nb = (ip < 3) ? tb
                               : (p7 < NPT - 1 ? tb + TILEU : tb);   // last pass: dummy in-bounds
                const int  pj = (ip < 3) ? (2 * ip + 2) : 0;
                PAIR_LOAD(P0, P1, P2, P3, P4, P5, P6, P7, nb, pj);
            }
            TAP_COMPUTE(4 * ip + 2, Q0, Q1, Q2, Q3);
            TAP_COMPUTE(4 * ip + 3, Q4, Q5, Q6, Q7);
        }

        // epilogue: d = s[pos] - 2*xp + p2[proto]; min over this wave's 64 positions
        // (also covers the in-flight next-pass P loads)
        // C layout (verified m74/m101): col = lane&31, row = (reg&3) + 8*(reg>>2) + 4*(lane>>5)
        const float p2v = p2g[p7 * 32 + m];
        float dmin = 3.4e38f;
        #pragma unroll
        for (int reg = 0; reg < 16; ++reg) {
            const int row = (reg & 3) + 8 * (reg >> 2) + 4 * half;
            float d0 = gwin[wv * 64 + row]      - 2.f * acc0[reg] + p2v;
            float d1 = gwin[wv * 64 + 32 + row] - 2.f * acc1[reg] + p2v;
            dmin = fminf(dmin, fminf(d0, d1));
        }
        dmin = fminf(dmin, __shfl_xor(dmin, 32));   // merge the two half-wave row sets
        if (half == 0 && p7 * 32 + m < PN)
            atomicMin(&wsm[b * PN + p7 * 32 + m], (u32)__float_as_uint(fmaxf(dmin, 0.f)));
    }
}

// K2: one block per batch; sole writer of d_out (f32: [0:320) logits, [320:6720) md).
// Kernel-launch boundary provides the device-wide sync/visibility (no fence needed).
__global__ void __launch_bounds__(256) k_head(const u32* __restrict__ wsm,
                                              const float* __restrict__ lw,
                                              float* __restrict__ out) {
    __shared__ float as_[PN];
    const int b = blockIdx.x, t = threadIdx.x;
    if (t < PN) {
        float md = __uint_as_float(wsm[b * PN + t]);
        md = fminf(fmaxf(md, 0.f), 2000.f);
        if (!(md == md)) md = 0.f;
        out[MD0 + b * PN + t] = md;
        as_[t] = logf((md + 1.f) / (md + EPSV));
    }
    __syncthreads();
    if (t < NCLS) {
        float sum = 0.f;
        #pragma unroll 1
        for (int p = 0; p < PN; ++p) sum += as_[p] * lw[t * PN + p];
        sum = fminf(fmaxf(sum, -100.f), 100.f);
        if (!(sum == sum)) sum = 0.f;
        out[b * NCLS + t] = sum;
    }
}

extern "C" void kernel_launch(void* const* d_in, const int* in_sizes, int n_in,
                              void* d_out, int out_size, void* d_ws, size_t ws_size,
                              hipStream_t stream) {
    // Inputs are FLOAT32. Resolve by unique element count (order-proof).
    const float* x  = 0;   // 32*16*8192 = 4194304
    const float* we = 0;   // 64*16*3    = 3072
    const float* wa = 0;   // 64*64*1    = 4096
    const float* pt = 0;   // 200*64*16  = 204800
    const float* lw = 0;   // 10*200     = 2000
    for (int i = 0; i < n_in; ++i) {
        switch (in_sizes[i]) {
            case 4194304: x  = (const float*)d_in[i]; break;
            case 3072:    we = (const float*)d_in[i]; break;
            case 4096:    wa = (const float*)d_in[i]; break;
            case 204800:  pt = (const float*)d_in[i]; break;
            case 2000:    lw = (const float*)d_in[i]; break;
            default: break;
        }
    }
    if (!x || !we || !wa || !pt || !lw) {
        x  = (const float*)d_in[0];
        we = (const float*)d_in[1];
        wa = (const float*)d_in[2];
        pt = (const float*)d_in[3];
        lw = (const float*)d_in[4];
    }
    float* out = (float*)d_out;   // f32: [0:320) logits, [320:6720) min_distances

    // Workspace layout (all 16B-aligned):
    char* ws  = (char*)d_ws;
    u32*   wsm = (u32*)ws;                 // 25600 B
    float* p2g = (float*)(ws + 25600);     // 896 B   -> 26496
    u16*   pk  = (u16*)(ws + 26496);       // 917504  -> 944000
    u16*   wpk = (u16*)(ws + 944000);      // 14336   -> 958336
    u16*   xT  = (u16*)(ws + 958336);      // 8454144 -> 9412480 (~9.0 MB total)

    k_prep<<<dim3(NTRB + 64), dim3(256), 0, stream>>>(x, we, wa, pt, wsm, p2g, pk, wpk, xT);
    k_dist<<<dim3(32, 32), dim3(256), 0, stream>>>(xT, wpk, pk, wsm, p2g);
    k_head<<<dim3(B_), dim3(256), 0, stream>>>(wsm, lw, out);
}

// Round 16
// 200.628 us; speedup vs baseline: 4.9490x; 4.9490x over previous
//
#include <hip/hip_runtime.h>
#include <hip/hip_bf16.h>
#include <math.h>

// Problem constants
#define B_    32
#define FIN   16
#define LIN   8192
#define LAT   64
#define L1V   8190      // length after k=3 valid conv
#define PN    200
#define PLEN  16
#define LOV   8175      // L1V - 16 + 1
#define NCLS  10
#define EPSV  1e-4f
#define MD0   320       // f32 offset of min_distances in d_out
#define CHK   256       // positions per block (R7-proven)
#define WIN   272       // window slots (CHK + 16)
#define FST   68        // fwin row stride in u16 (136 B: 2-way bank aliasing = free)
#define NPT   7         // proto tiles of 32 (200 padded to 224)
#define NFRAG (NPT * 16 * 4 * 64)   // 28672 pre-packed proto B-fragments
#define XSLOT 8256      // padded x slots per batch (zero tail; max read = 8225)
#define NTRB  (33 * B_) // transpose blocks: 33 tiles of 256 slots x 32 batches

typedef unsigned short u16;
typedef unsigned int   u32;
typedef short s16x8 __attribute__((ext_vector_type(8)));   // 8 bf16 (4 VGPRs)
typedef float f32x16 __attribute__((ext_vector_type(16))); // 32x32 MFMA accumulator

union FragU { uint2 u2[2]; s16x8 v; };

__device__ __forceinline__ u16 vf2b(float f) {
    union { float f; u32 u; } v; v.f = f;
    u32 u = v.u;
    return (u16)((u + 0x7fffu + ((u >> 16) & 1u)) >> 16);   // RNE
}

// K0 (fused prep): identical to R12/R14 (best measured).
//  blocks [0, NTRB): LDS-tiled transpose x -> xT bf16 [b][slot][16 ci], zero-padded.
//  blocks [NTRB, NTRB+64): wsm = FLT_MAX bits; p2g = ||proto||^2 (wave-parallel);
//    pk/wpk B-frag packs.
__global__ void k_prep(const float* __restrict__ x, const float* __restrict__ we,
                       const float* __restrict__ wa, const float* __restrict__ pt,
                       u32* __restrict__ wsm, float* __restrict__ p2g,
                       u16* __restrict__ pk, u16* __restrict__ wpk,
                       u16* __restrict__ xT) {
    __shared__ u16 ls[16][256];          // 8 KB (transpose blocks only)
    const int t = threadIdx.x;

    if (blockIdx.x < NTRB) {
        // ---- coalesced transpose tile: batch b, slots [base, base+256) ----
        const int tile = blockIdx.x % 33;
        const int b    = blockIdx.x / 33;
        const int base = tile * 256;
        const float* xb = x + (size_t)b * FIN * LIN;
        const int slot = base + t;
        #pragma unroll
        for (int ch = 0; ch < 16; ++ch) {
            float v = (slot < LIN) ? xb[(size_t)ch * LIN + slot] : 0.f;
            ls[ch][t] = vf2b(v);
        }
        __syncthreads();
        if (slot < XSLOT) {
            u32 w[8];
            #pragma unroll
            for (int cp = 0; cp < 8; ++cp)
                w[cp] = ((u32)ls[2 * cp + 1][t] << 16) | (u32)ls[2 * cp][t];
            uint4* dst = (uint4*)(xT + ((size_t)b * XSLOT + slot) * 16);
            dst[0] = make_uint4(w[0], w[1], w[2], w[3]);
            dst[1] = make_uint4(w[4], w[5], w[6], w[7]);
        }
        return;
    }

    // ---- misc packing (grid-strided over 64 blocks x 256 threads) ----
    const int tid = (blockIdx.x - NTRB) * 256 + t;
    const int N   = 64 * 256;

    for (int j = tid; j < B_ * PN; j += N) wsm[j] = 0x7f7fffffu;

    // p2g wave-parallel: one wave per proto, lane sums 16 f32, butterfly reduce
    {
        const int wid = tid >> 6, nl = tid & 63, NW = N >> 6;
        for (int p = wid; p < 224; p += NW) {
            float s = 0.f;
            if (p < PN) {
                const float4* pr = (const float4*)(pt + (size_t)p * (LAT * PLEN)) + nl * 4;
                #pragma unroll
                for (int j = 0; j < 4; ++j) {
                    float4 v = pr[j];
                    s += v.x * v.x + v.y * v.y + v.z * v.z + v.w * v.w;
                }
            }
            #pragma unroll
            for (int off = 32; off; off >>= 1) s += __shfl_xor(s, off);
            if (nl == 0) p2g[p] = s;
        }
    }

    // pk: protos as per-lane MFMA B-frags (col=lane&31 proto, k=(lane>>5)*8+j ch, per tap/cs)
    for (int f = tid; f < NFRAG; f += N) {
        const int lane = f & 63;
        const int cs   = (f >> 6) & 3;
        const int tap  = (f >> 8) & 15;
        const int p7   = f >> 12;
        const int gp   = p7 * 32 + (lane & 31);
        const int chb  = cs * 16 + (lane >> 5) * 8;
        s16x8 v;
        if (gp < PN) {
            const float* src = pt + (size_t)gp * (LAT * PLEN) + (size_t)chb * PLEN + tap;
            #pragma unroll
            for (int j = 0; j < 8; ++j) v[j] = (short)vf2b(src[j * PLEN]);
        } else {
            #pragma unroll
            for (int j = 0; j < 8; ++j) v[j] = 0;
        }
        *(s16x8*)(pk + (size_t)f * 8) = v;
    }

    // wpk: 14 encoder B-frag groups x 64 lanes
    // grp 0..5 = we[tap 0..2][ntile 0..1] (K=16 ci); grp 6..13 = wa[cs 0..3][ntile 0..1]
    for (int f = tid; f < 14 * 64; f += N) {
        const int lane = f & 63, grp = f >> 6;
        const int col = lane & 31, kb = (lane >> 5) * 8;
        s16x8 v;
        if (grp < 6) {
            const int tau = grp >> 1, nt = grp & 1;
            #pragma unroll
            for (int j = 0; j < 8; ++j)
                v[j] = (short)vf2b(we[(size_t)(nt * 32 + col) * 48 + (kb + j) * 3 + tau]);
        } else {
            const int g2 = grp - 6, cs = g2 >> 1, nt = g2 & 1;
            #pragma unroll
            for (int j = 0; j < 8; ++j)
                v[j] = (short)vf2b(wa[(size_t)(nt * 32 + col) * 64 + cs * 16 + kb + j]);
        }
        *(s16x8*)(wpk + (size_t)f * 8) = v;
    }
}

// One tap's compute: 4 cs slices, A from LDS, B from the given register set.
#define TAP_COMPUTE(TAP, B0, B1, B2, B3)                                            \
    {                                                                               \
        const u16* apb = &fwin[(wv * 64 + m + (TAP)) * FST + koff];                 \
        FragU a0, a1;                                                               \
        a0.u2[0] = *(const uint2*)(apb);        a0.u2[1] = *(const uint2*)(apb + 4);\
        a1.u2[0] = *(const uint2*)(apb + 32*FST); a1.u2[1] = *(const uint2*)(apb + 32*FST + 4);\
        acc0 = __builtin_amdgcn_mfma_f32_32x32x16_bf16(a0.v, B0.v, acc0, 0, 0, 0);  \
        acc1 = __builtin_amdgcn_mfma_f32_32x32x16_bf16(a1.v, B0.v, acc1, 0, 0, 0);  \
        a0.u2[0] = *(const uint2*)(apb + 16);   a0.u2[1] = *(const uint2*)(apb + 20);\
        a1.u2[0] = *(const uint2*)(apb + 32*FST + 16); a1.u2[1] = *(const uint2*)(apb + 32*FST + 20);\
        acc0 = __builtin_amdgcn_mfma_f32_32x32x16_bf16(a0.v, B1.v, acc0, 0, 0, 0);  \
        acc1 = __builtin_amdgcn_mfma_f32_32x32x16_bf16(a1.v, B1.v, acc1, 0, 0, 0);  \
        a0.u2[0] = *(const uint2*)(apb + 32);   a0.u2[1] = *(const uint2*)(apb + 36);\
        a1.u2[0] = *(const uint2*)(apb + 32*FST + 32); a1.u2[1] = *(const uint2*)(apb + 32*FST + 36);\
        acc0 = __builtin_amdgcn_mfma_f32_32x32x16_bf16(a0.v, B2.v, acc0, 0, 0, 0);  \
        acc1 = __builtin_amdgcn_mfma_f32_32x32x16_bf16(a1.v, B2.v, acc1, 0, 0, 0);  \
        a0.u2[0] = *(const uint2*)(apb + 48);   a0.u2[1] = *(const uint2*)(apb + 52);\
        a1.u2[0] = *(const uint2*)(apb + 32*FST + 48); a1.u2[1] = *(const uint2*)(apb + 32*FST + 52);\
        acc0 = __builtin_amdgcn_mfma_f32_32x32x16_bf16(a0.v, B3.v, acc0, 0, 0, 0);  \
        acc1 = __builtin_amdgcn_mfma_f32_32x32x16_bf16(a1.v, B3.v, acc1, 0, 0, 0);  \
    }

// K1: block = (chunk of 256 positions, batch); grid 32x32, 4 blocks/CU fully resident.
// Phases 1-2 identical to R7/R12 (measured 123.5us, MfmaUtil 45%).
// Phase 3: depth-1 register ping-pong of B-frags (R14, measured k_dist 116.3us,
// MfmaUtil ~49%, VGPR 60). Depth-2 (R15) exceeded the 128-VGPR budget at 4 blk/CU
// and spilled to scratch (FETCH 6.6MB->1.76GB): depth-1 is the max at this occupancy.
__global__ void __launch_bounds__(256, 4) k_dist(const u16* __restrict__ xT,
                                                 const u16* __restrict__ wpk,
                                                 const u16* __restrict__ pk,
                                                 u32* __restrict__ wsm,
                                                 const float* __restrict__ p2g) {
    __shared__ __align__(16) u16 fwin[WIN * FST];    // 36992 B, [slot][ch] bf16
    __shared__ float gwin[WIN];                      // 1088 B; g then s (-> 4 blk/CU)

    const int t  = threadIdx.x;
    const int ck = blockIdx.x;           // 0..31
    const int b  = blockIdx.y;           // 0..31
    const int base = ck * CHK;

    const int lane = t & 63;
    const int wv   = t >> 6;
    const int m    = lane & 31;
    const int half = lane >> 5;
    const int koff = half * 8;

    const u16* wpkl = wpk + (size_t)lane * 8;
    const u16* xTb  = xT + (size_t)b * XSLOT * 16;

    // ---------------- Phase 1: MFMA encoder ----------------
    #pragma unroll 1
    for (int mt = wv; mt < 9; mt += 4) {
        const int ar = mt * 32 + m;                  // this lane's A row
        // GEMM1: f1 = relu(conv3(x)), tap-decomposed, K=16 ci per tap
        f32x16 c1[2];
        #pragma unroll
        for (int i = 0; i < 16; ++i) { c1[0][i] = 0.f; c1[1][i] = 0.f; }
        #pragma unroll
        for (int tau = 0; tau < 3; ++tau) {
            FragU aF;
            aF.v = *(const s16x8*)(xTb + (size_t)(base + ar + tau) * 16 + koff);
            #pragma unroll
            for (int nt = 0; nt < 2; ++nt) {
                FragU bW; bW.v = *(const s16x8*)(wpkl + (size_t)(tau * 2 + nt) * 512);
                c1[nt] = __builtin_amdgcn_mfma_f32_32x32x16_bf16(aF.v, bW.v, c1[nt], 0, 0, 0);
            }
        }
        // write f1 (relu, bf16) into fwin rows of this tile (mask rows >= WIN for tile 8)
        #pragma unroll
        for (int nt = 0; nt < 2; ++nt) {
            const int col = nt * 32 + m;
            #pragma unroll
            for (int reg = 0; reg < 16; ++reg) {
                const int row = mt * 32 + (reg & 3) + 8 * (reg >> 2) + 4 * half;
                if (row < WIN) fwin[row * FST + col] = vf2b(fmaxf(c1[nt][reg], 0.f));
            }
        }
        // GEMM2: f2 = relu(wa . f1), K=64 in 4 cs slices; reads then overwrites same rows
        f32x16 c2[2];
        #pragma unroll
        for (int i = 0; i < 16; ++i) { c2[0][i] = 0.f; c2[1][i] = 0.f; }
        FragU a2[4];
        const int arc = (ar < WIN) ? ar : (WIN - 1);     // clamp tile-8 dead rows (stay in tile)
        #pragma unroll
        for (int cs = 0; cs < 4; ++cs) {
            const u16* ap = &fwin[arc * FST + cs * 16 + koff];
            a2[cs].u2[0] = *(const uint2*)ap;
            a2[cs].u2[1] = *(const uint2*)(ap + 4);
        }
        #pragma unroll
        for (int cs = 0; cs < 4; ++cs)
            #pragma unroll
            for (int nt = 0; nt < 2; ++nt) {
                FragU bW; bW.v = *(const s16x8*)(wpkl + (size_t)(6 + cs * 2 + nt) * 512);
                c2[nt] = __builtin_amdgcn_mfma_f32_32x32x16_bf16(a2[cs].v, bW.v, c2[nt], 0, 0, 0);
            }
        #pragma unroll
        for (int nt = 0; nt < 2; ++nt) {
            const int col = nt * 32 + m;
            #pragma unroll
            for (int reg = 0; reg < 16; ++reg) {
                const int row = mt * 32 + (reg & 3) + 8 * (reg >> 2) + 4 * half;
                if (row < WIN) fwin[row * FST + col] = vf2b(fmaxf(c2[nt][reg], 0.f));
            }
        }
    }
    __syncthreads();

    // ---------------- Phase 2a: per-slot g = ||f2||^2 ----------------
    {
        float g0 = 0.f, g1 = 0.f;
        const uint2* r0 = (const uint2*)(fwin + (size_t)t * FST);
        #pragma unroll
        for (int i = 0; i < 16; ++i) {
            uint2 v = r0[i];
            float a = __uint_as_float(v.x << 16);
            float bb = __uint_as_float(v.x & 0xffff0000u);
            float c = __uint_as_float(v.y << 16);
            float d = __uint_as_float(v.y & 0xffff0000u);
            g0 += a * a + bb * bb + c * c + d * d;
        }
        if (t < 16) {
            const uint2* r1 = (const uint2*)(fwin + (size_t)(CHK + t) * FST);
            #pragma unroll
            for (int i = 0; i < 16; ++i) {
                uint2 v = r1[i];
                float a = __uint_as_float(v.x << 16);
                float bb = __uint_as_float(v.x & 0xffff0000u);
                float c = __uint_as_float(v.y << 16);
                float d = __uint_as_float(v.y & 0xffff0000u);
                g1 += a * a + bb * bb + c * c + d * d;
            }
        }
        gwin[t] = g0;
        if (t < 16) gwin[CHK + t] = g1;
    }
    __syncthreads();

    // ---------------- Phase 2b: sliding patch-norm (poison tail), overwrite gwin ----
    {
        float sv = 0.f;
        #pragma unroll
        for (int k = 0; k < PLEN; ++k) sv += gwin[t + k];
        sv = (base + t < LOV) ? sv : 3.0e38f;
        __syncthreads();
        gwin[t] = sv;
    }
    __syncthreads();

    // ---------------- Phase 3: distance GEMM with B register ping-pong ----------------
    #pragma unroll 1
    for (int p7 = 0; p7 < NPT; ++p7) {
        f32x16 acc0, acc1;
        #pragma unroll
        for (int i = 0; i < 16; ++i) { acc0[i] = 0.f; acc1[i] = 0.f; }

        const u16* pkb = pk + (size_t)p7 * (16 * 4 * 64 * 8) + (size_t)lane * 8;

        FragU pA0, pA1, pA2, pA3, pB0, pB1, pB2, pB3;
        pA0.v = *(const s16x8*)(pkb + 0 * 512);
        pA1.v = *(const s16x8*)(pkb + 1 * 512);
        pA2.v = *(const s16x8*)(pkb + 2 * 512);
        pA3.v = *(const s16x8*)(pkb + 3 * 512);

        #pragma unroll 1
        for (int tp = 0; tp < 8; ++tp) {
            const int te = 2 * tp, to = 2 * tp + 1;
            // prefetch odd tap's B while computing even tap from pA*
            pB0.v = *(const s16x8*)(pkb + (size_t)(to * 4 + 0) * 512);
            pB1.v = *(const s16x8*)(pkb + (size_t)(to * 4 + 1) * 512);
            pB2.v = *(const s16x8*)(pkb + (size_t)(to * 4 + 2) * 512);
            pB3.v = *(const s16x8*)(pkb + (size_t)(to * 4 + 3) * 512);
            TAP_COMPUTE(te, pA0, pA1, pA2, pA3);
            // prefetch next even tap's B while computing odd tap from pB*
            if (tp < 7) {
                pA0.v = *(const s16x8*)(pkb + (size_t)((te + 2) * 4 + 0) * 512);
                pA1.v = *(const s16x8*)(pkb + (size_t)((te + 2) * 4 + 1) * 512);
                pA2.v = *(const s16x8*)(pkb + (size_t)((te + 2) * 4 + 2) * 512);
                pA3.v = *(const s16x8*)(pkb + (size_t)((te + 2) * 4 + 3) * 512);
            }
            TAP_COMPUTE(to, pB0, pB1, pB2, pB3);
        }

        // epilogue: d = s[pos] - 2*xp + p2[proto]; min over this wave's 64 positions
        // C layout (verified m74/m101): col = lane&31, row = (reg&3) + 8*(reg>>2) + 4*(lane>>5)
        const float p2v = p2g[p7 * 32 + m];
        float dmin = 3.4e38f;
        #pragma unroll
        for (int reg = 0; reg < 16; ++reg) {
            const int row = (reg & 3) + 8 * (reg >> 2) + 4 * half;
            float d0 = gwin[wv * 64 + row]      - 2.f * acc0[reg] + p2v;
            float d1 = gwin[wv * 64 + 32 + row] - 2.f * acc1[reg] + p2v;
            dmin = fminf(dmin, fminf(d0, d1));
        }
        dmin = fminf(dmin, __shfl_xor(dmin, 32));   // merge the two half-wave row sets
        if (half == 0 && p7 * 32 + m < PN)
            atomicMin(&wsm[b * PN + p7 * 32 + m], (u32)__float_as_uint(fmaxf(dmin, 0.f)));
    }
}

// K2: one block per batch; sole writer of d_out (f32: [0:320) logits, [320:6720) md).
// Kernel-launch boundary provides the device-wide sync/visibility (no fence needed).
__global__ void __launch_bounds__(256) k_head(const u32* __restrict__ wsm,
                                              const float* __restrict__ lw,
                                              float* __restrict__ out) {
    __shared__ float as_[PN];
    const int b = blockIdx.x, t = threadIdx.x;
    if (t < PN) {
        float md = __uint_as_float(wsm[b * PN + t]);
        md = fminf(fmaxf(md, 0.f), 2000.f);
        if (!(md == md)) md = 0.f;
        out[MD0 + b * PN + t] = md;
        as_[t] = logf((md + 1.f) / (md + EPSV));
    }
    __syncthreads();
    if (t < NCLS) {
        float sum = 0.f;
        #pragma unroll 1
        for (int p = 0; p < PN; ++p) sum += as_[p] * lw[t * PN + p];
        sum = fminf(fmaxf(sum, -100.f), 100.f);
        if (!(sum == sum)) sum = 0.f;
        out[b * NCLS + t] = sum;
    }
}

extern "C" void kernel_launch(void* const* d_in, const int* in_sizes, int n_in,
                              void* d_out, int out_size, void* d_ws, size_t ws_size,
                              hipStream_t stream) {
    // Inputs are FLOAT32. Resolve by unique element count (order-proof).
    const float* x  = 0;   // 32*16*8192 = 4194304
    const float* we = 0;   // 64*16*3    = 3072
    const float* wa = 0;   // 64*64*1    = 4096
    const float* pt = 0;   // 200*64*16  = 204800
    const float* lw = 0;   // 10*200     = 2000
    for (int i = 0; i < n_in; ++i) {
        switch (in_sizes[i]) {
            case 4194304: x  = (const float*)d_in[i]; break;
            case 3072:    we = (const float*)d_in[i]; break;
            case 4096:    wa = (const float*)d_in[i]; break;
            case 204800:  pt = (const float*)d_in[i]; break;
            case 2000:    lw = (const float*)d_in[i]; break;
            default: break;
        }
    }
    if (!x || !we || !wa || !pt || !lw) {
        x  = (const float*)d_in[0];
        we = (const float*)d_in[1];
        wa = (const float*)d_in[2];
        pt = (const float*)d_in[3];
        lw = (const float*)d_in[4];
    }
    float* out = (float*)d_out;   // f32: [0:320) logits, [320:6720) min_distances

    // Workspace layout (all 16B-aligned):
    char* ws  = (char*)d_ws;
    u32*   wsm = (u32*)ws;                 // 25600 B
    float* p2g = (float*)(ws + 25600);     // 896 B   -> 26496
    u16*   pk  = (u16*)(ws + 26496);       // 917504  -> 944000
    u16*   wpk = (u16*)(ws + 944000);      // 14336   -> 958336
    u16*   xT  = (u16*)(ws + 958336);      // 8454144 -> 9412480 (~9.0 MB total)

    k_prep<<<dim3(NTRB + 64), dim3(256), 0, stream>>>(x, we, wa, pt, wsm, p2g, pk, wpk, xT);
    k_dist<<<dim3(32, 32), dim3(256), 0, stream>>>(xT, wpk, pk, wsm, p2g);
    k_head<<<dim3(B_), dim3(256), 0, stream>>>(wsm, lw, out);
}